// Round 8
// baseline (830.088 us; speedup 1.0000x reference)
//
#include <hip/hip_runtime.h>
#include <hip/hip_bf16.h>
#include <hip/hip_cooperative_groups.h>
#include <math.h>

namespace cg = cooperative_groups;

#define NFEAT 500
#define KPAD  512
#define NHID  256
#define NCLS  64
#define KPOLY 10

#define NBLK    1024            // 4 blocks/CU * 256 CU (conservative for coop residency)
#define WPB     4               // waves per block
#define ROWS_PW 25              // ceil(100000 / (1024*4))

typedef __attribute__((ext_vector_type(8))) short short8;
typedef __attribute__((ext_vector_type(4))) float f32x4;

__device__ inline unsigned short bf16_rn(float v) {
  unsigned u = __float_as_uint(v);
  return (unsigned short)((u + 0x7FFFu + ((u >> 16) & 1u)) >> 16);
}
__device__ inline float u2f_lo(unsigned u) { return __uint_as_float(u << 16); }
__device__ inline float u2f_hi(unsigned u) { return __uint_as_float(u & 0xFFFF0000u); }
__device__ inline unsigned pack2(float a, float b) {
  return (unsigned)bf16_rn(a) | ((unsigned)bf16_rn(b) << 16);
}
__device__ inline void split2(float v, unsigned short& hi, unsigned short& lo) {
  unsigned short h = bf16_rn(v);
  float vh = __uint_as_float(((unsigned)h) << 16);
  lo = bf16_rn(v - vh);
  hi = h;
}

// ---------- weight pre-conversion into MFMA fragment layout ----------
__global__ void conv_w1f(const float* __restrict__ W1, unsigned short* __restrict__ Fh,
                         unsigned short* __restrict__ Fl) {
  int i = blockIdx.x * 256 + threadIdx.x;
  if (i >= KPAD * NHID) return;
  int kg = i >> 11, c = (i >> 3) & 255, kin = i & 7;
  int k = kg * 8 + kin;
  float v = (k < NFEAT) ? W1[c * NFEAT + k] : 0.0f;
  unsigned short h, l;
  split2(v, h, l);
  Fh[i] = h; Fl[i] = l;
}
__global__ void conv_w2f(const float* __restrict__ W2, unsigned short* __restrict__ F) {
  int i = blockIdx.x * 256 + threadIdx.x;
  if (i >= NHID * NCLS) return;
  int kg = i >> 9, c = (i >> 3) & 63, kin = i & 7;
  int k = kg * 8 + kin;
  F[i] = bf16_rn(W2[c * NHID + k]);
}

// ------------------------- CSR build -------------------------
__global__ void edge_count(const int* __restrict__ ei, int E,
                           int* __restrict__ deg, int* __restrict__ cnt) {
  int stride = gridDim.x * blockDim.x;
  for (int e = blockIdx.x * blockDim.x + threadIdx.x; e < E; e += stride) {
    int r = ei[e], c = ei[E + e];
    atomicAdd(&cnt[r], 1);
    if (r != c) atomicAdd(&deg[r], 1);
  }
}

__global__ void make_dinv(const int* __restrict__ deg, float* __restrict__ dinv, int n) {
  int i = blockIdx.x * blockDim.x + threadIdx.x;
  if (i < n) {
    int d = deg[i];
    dinv[i] = (d > 0) ? rsqrtf((float)d) : 0.0f;
  }
}

__global__ void scan_block(const int* __restrict__ cnt, int* __restrict__ rowptr,
                           int* __restrict__ bsums, int n) {
  __shared__ int s[256];
  int i = blockIdx.x * 256 + threadIdx.x;
  int v = (i < n) ? cnt[i] : 0;
  s[threadIdx.x] = v;
  __syncthreads();
  for (int off = 1; off < 256; off <<= 1) {
    int t = (threadIdx.x >= (unsigned)off) ? s[threadIdx.x - off] : 0;
    __syncthreads();
    s[threadIdx.x] += t;
    __syncthreads();
  }
  if (i < n) rowptr[i + 1] = s[threadIdx.x];
  if (threadIdx.x == 255) bsums[blockIdx.x] = s[255];
}

__global__ void scan_sums(int* __restrict__ bsums, int nb, int* __restrict__ rowptr) {
  if (threadIdx.x == 0 && blockIdx.x == 0) {
    int run = 0;
    for (int b = 0; b < nb; ++b) { int t = bsums[b]; bsums[b] = run; run += t; }
    rowptr[0] = 0;
  }
}

__global__ void scan_add(int* __restrict__ rowptr, const int* __restrict__ bsums, int n) {
  int i = blockIdx.x * 256 + threadIdx.x;
  if (i < n) rowptr[i + 1] += bsums[i >> 8];
}

__global__ void scatter_edges(const int* __restrict__ ei, int E,
                              const float* __restrict__ dinv,
                              const int* __restrict__ rowptr, int* __restrict__ cur,
                              int2* __restrict__ ecw) {
  int stride = gridDim.x * blockDim.x;
  for (int e = blockIdx.x * blockDim.x + threadIdx.x; e < E; e += stride) {
    int r = ei[e], c = ei[E + e];
    int pos = rowptr[r] + atomicAdd(&cur[r], 1);
    float wt = (r != c) ? (-dinv[r] * dinv[c]) : 0.0f;
    ecw[pos] = make_int2(c, __float_as_int(wt));
  }
}

// ------------------------- fused MLP via MFMA (bf16 hi/lo split) -------------------------
__global__ __launch_bounds__(256, 4) void mlp_mfma(
    const float* __restrict__ x, const unsigned short* __restrict__ W1Fh,
    const unsigned short* __restrict__ W1Fl, const unsigned short* __restrict__ W2F,
    unsigned short* __restrict__ hout, int n)
{
  __shared__ union {
    struct { unsigned short Ah[4][64][8], Al[4][64][8]; } g1;   // 8 KB
    struct { unsigned short A2[32][64][8]; } g2;                // 32 KB
  } u;

  const int tid = threadIdx.x;
  const int w = tid >> 6;
  const int l = tid & 63;
  const int l15 = l & 15, l4 = l >> 4;
  const int row0 = blockIdx.x * 64;

  f32x4 acc[4][4];
  const f32x4 zf = {0.0f, 0.0f, 0.0f, 0.0f};
#pragma unroll
  for (int i = 0; i < 4; ++i)
#pragma unroll
    for (int j = 0; j < 4; ++j) acc[i][j] = zf;

  for (int t = 0; t < 16; ++t) {
    const int k0 = t * 32;
    short8 bH[4], bL[4];
#pragma unroll
    for (int nf = 0; nf < 4; ++nf) {
      size_t bi = (size_t)t * 8192 + ((size_t)l4 * 256 + w * 64 + nf * 16 + l15) * 8;
      bH[nf] = *(const short8*)(W1Fh + bi);
      bL[nf] = *(const short8*)(W1Fl + bi);
    }
#pragma unroll
    for (int s = 0; s < 2; ++s) {
      int f = tid + s * 256;
      int r = f >> 3, slot = f & 7;
      int gr = row0 + r, gk = k0 + slot * 4;
      float4 v = make_float4(0.f, 0.f, 0.f, 0.f);
      if (gr < n && gk + 3 < NFEAT)
        v = *(const float4*)&x[(size_t)gr * NFEAT + gk];
      unsigned short a0, a1, a2, a3, b0, b1, b2, b3;
      split2(v.x, a0, b0); split2(v.y, a1, b1); split2(v.z, a2, b2); split2(v.w, a3, b3);
      int kg = slot >> 1, kin0 = (slot & 1) * 4;
      *(uint2*)&u.g1.Ah[kg][r][kin0] =
          make_uint2((unsigned)a0 | ((unsigned)a1 << 16), (unsigned)a2 | ((unsigned)a3 << 16));
      *(uint2*)&u.g1.Al[kg][r][kin0] =
          make_uint2((unsigned)b0 | ((unsigned)b1 << 16), (unsigned)b2 | ((unsigned)b3 << 16));
    }
    __syncthreads();

#pragma unroll
    for (int mf = 0; mf < 4; ++mf) {
      short8 aH = *(const short8*)&u.g1.Ah[l4][mf * 16 + l15][0];
      short8 aL = *(const short8*)&u.g1.Al[l4][mf * 16 + l15][0];
#pragma unroll
      for (int nf = 0; nf < 4; ++nf) {
        acc[mf][nf] = __builtin_amdgcn_mfma_f32_16x16x32_bf16(aH, bH[nf], acc[mf][nf], 0, 0, 0);
        acc[mf][nf] = __builtin_amdgcn_mfma_f32_16x16x32_bf16(aH, bL[nf], acc[mf][nf], 0, 0, 0);
        acc[mf][nf] = __builtin_amdgcn_mfma_f32_16x16x32_bf16(aL, bH[nf], acc[mf][nf], 0, 0, 0);
      }
    }
    __syncthreads();
  }

#pragma unroll
  for (int mf = 0; mf < 4; ++mf)
#pragma unroll
    for (int nf = 0; nf < 4; ++nf) {
      int col = w * 64 + nf * 16 + l15;
      int kg = col >> 3, kin = col & 7;
#pragma unroll
      for (int j = 0; j < 4; ++j) {
        float vv = fmaxf(acc[mf][nf][j], 0.0f);
        u.g2.A2[kg][mf * 16 + l4 * 4 + j][kin] = bf16_rn(vv);
      }
    }
  __syncthreads();

  f32x4 acc2[4];
#pragma unroll
  for (int i = 0; i < 4; ++i) acc2[i] = zf;
#pragma unroll
  for (int ks = 0; ks < 8; ++ks) {
    short8 a2 = *(const short8*)&u.g2.A2[ks * 4 + l4][w * 16 + l15][0];
#pragma unroll
    for (int nf2 = 0; nf2 < 4; ++nf2) {
      size_t bi = ((size_t)(ks * 4 + l4) * 64 + nf2 * 16 + l15) * 8;
      short8 b2 = *(const short8*)(W2F + bi);
      acc2[nf2] = __builtin_amdgcn_mfma_f32_16x16x32_bf16(a2, b2, acc2[nf2], 0, 0, 0);
    }
  }
#pragma unroll
  for (int nf2 = 0; nf2 < 4; ++nf2)
#pragma unroll
    for (int j = 0; j < 4; ++j) {
      int r = row0 + w * 16 + l4 * 4 + j;
      if (r < n) hout[(size_t)r * NCLS + nf2 * 16 + l15] = bf16_rn(acc2[nf2][j]);
    }
}

// ------------------------- gather: 8 lanes/edge, uint4 row-slices ------------------------
__device__ inline void gather_row8(const int* __restrict__ rowptr,
                                   const int2* __restrict__ ecw,
                                   const unsigned short* __restrict__ src,
                                   int row, int p, float s[8]) {
#pragma unroll
  for (int i = 0; i < 8; ++i) s[i] = 0.0f;
  int e0 = rowptr[row], e1 = rowptr[row + 1];
  int gg = (threadIdx.x & 63) >> 3;
  for (int e = e0; e < e1; e += 16) {
    int eeA = e + gg, eeB = e + 8 + gg;
    int eA = (eeA < e1) ? eeA : (e1 - 1);
    int eB = (eeB < e1) ? eeB : (e1 - 1);
    int2 tA = ecw[eA];
    int2 tB = ecw[eB];
    uint4 hA = *(const uint4*)(src + (((size_t)tA.x) << 6) + (p << 3));
    uint4 hB = *(const uint4*)(src + (((size_t)tB.x) << 6) + (p << 3));
    float wA = (eeA < e1) ? __int_as_float(tA.y) : 0.0f;
    float wB = (eeB < e1) ? __int_as_float(tB.y) : 0.0f;
    s[0] = fmaf(wA, u2f_lo(hA.x), s[0]); s[1] = fmaf(wA, u2f_hi(hA.x), s[1]);
    s[2] = fmaf(wA, u2f_lo(hA.y), s[2]); s[3] = fmaf(wA, u2f_hi(hA.y), s[3]);
    s[4] = fmaf(wA, u2f_lo(hA.z), s[4]); s[5] = fmaf(wA, u2f_hi(hA.z), s[5]);
    s[6] = fmaf(wA, u2f_lo(hA.w), s[6]); s[7] = fmaf(wA, u2f_hi(hA.w), s[7]);
    s[0] = fmaf(wB, u2f_lo(hB.x), s[0]); s[1] = fmaf(wB, u2f_hi(hB.x), s[1]);
    s[2] = fmaf(wB, u2f_lo(hB.y), s[2]); s[3] = fmaf(wB, u2f_hi(hB.y), s[3]);
    s[4] = fmaf(wB, u2f_lo(hB.z), s[4]); s[5] = fmaf(wB, u2f_hi(hB.z), s[5]);
    s[6] = fmaf(wB, u2f_lo(hB.w), s[6]); s[7] = fmaf(wB, u2f_hi(hB.w), s[7]);
  }
#pragma unroll
  for (int i = 0; i < 8; ++i) {
    s[i] += __shfl_xor(s[i], 8, 64);
    s[i] += __shfl_xor(s[i], 16, 64);
    s[i] += __shfl_xor(s[i], 32, 64);
  }
}

// ------------------- cooperative fused Chebyshev chain + log-softmax -------------------
__global__ __launch_bounds__(256, 4) void spmm_chain(
    const int* __restrict__ rowptr, const int2* __restrict__ ecw,
    unsigned short* __restrict__ b0, unsigned short* __restrict__ b1,
    unsigned short* __restrict__ b2, float* __restrict__ out,
    const float* __restrict__ cw, int n)
{
  cg::grid_group grid = cg::this_grid();
  const int tid = threadIdx.x;
  const int w = tid >> 6, lane = tid & 63;
  const int p = lane & 7, g = lane >> 3;
  const int row0 = (blockIdx.x * WPB + w) * ROWS_PW;

  float acc[4][8];   // indexed only with unrolled-constant [i>>3]

  // ---- pass 1: T1 = A h; acc = cw0*h + cw1*T1 ----
  {
    float c0 = cw[0], c1 = cw[1];
#pragma unroll
    for (int i = 0; i < ROWS_PW; ++i) {
      int row = row0 + i;
      if (row < n) {
        float s[8];
        gather_row8(rowptr, ecw, b0, row, p, s);
        if (g == (i & 7)) {
          size_t base = (size_t)row * NCLS + (p << 3);
          uint4 hv = *(const uint4*)(b0 + base);
          acc[i >> 3][0] = c0 * u2f_lo(hv.x) + c1 * s[0];
          acc[i >> 3][1] = c0 * u2f_hi(hv.x) + c1 * s[1];
          acc[i >> 3][2] = c0 * u2f_lo(hv.y) + c1 * s[2];
          acc[i >> 3][3] = c0 * u2f_hi(hv.y) + c1 * s[3];
          acc[i >> 3][4] = c0 * u2f_lo(hv.z) + c1 * s[4];
          acc[i >> 3][5] = c0 * u2f_hi(hv.z) + c1 * s[5];
          acc[i >> 3][6] = c0 * u2f_lo(hv.w) + c1 * s[6];
          acc[i >> 3][7] = c0 * u2f_hi(hv.w) + c1 * s[7];
          uint4 tw;
          tw.x = pack2(s[0], s[1]); tw.y = pack2(s[2], s[3]);
          tw.z = pack2(s[4], s[5]); tw.w = pack2(s[6], s[7]);
          *(uint4*)(b1 + base) = tw;
        }
      }
    }
  }
  grid.sync();

  // ---- passes k = 2..KPOLY ----
  unsigned short *Pb = b0, *Cb = b1, *Nb = b2;
  for (int k = 2; k <= KPOLY; ++k) {
    float ck = cw[k];
    int last = (k == KPOLY);
#pragma unroll
    for (int i = 0; i < ROWS_PW; ++i) {
      int row = row0 + i;
      if (row < n) {
        float s[8];
        gather_row8(rowptr, ecw, Cb, row, p, s);
        if (g == (i & 7)) {
          size_t base = (size_t)row * NCLS + (p << 3);
          uint4 pv = *(const uint4*)(Pb + base);
          float t0 = 2.0f * s[0] - u2f_lo(pv.x), t1 = 2.0f * s[1] - u2f_hi(pv.x);
          float t2 = 2.0f * s[2] - u2f_lo(pv.y), t3 = 2.0f * s[3] - u2f_hi(pv.y);
          float t4 = 2.0f * s[4] - u2f_lo(pv.z), t5 = 2.0f * s[5] - u2f_hi(pv.z);
          float t6 = 2.0f * s[6] - u2f_lo(pv.w), t7 = 2.0f * s[7] - u2f_hi(pv.w);
          acc[i >> 3][0] = fmaf(ck, t0, acc[i >> 3][0]);
          acc[i >> 3][1] = fmaf(ck, t1, acc[i >> 3][1]);
          acc[i >> 3][2] = fmaf(ck, t2, acc[i >> 3][2]);
          acc[i >> 3][3] = fmaf(ck, t3, acc[i >> 3][3]);
          acc[i >> 3][4] = fmaf(ck, t4, acc[i >> 3][4]);
          acc[i >> 3][5] = fmaf(ck, t5, acc[i >> 3][5]);
          acc[i >> 3][6] = fmaf(ck, t6, acc[i >> 3][6]);
          acc[i >> 3][7] = fmaf(ck, t7, acc[i >> 3][7]);
          if (!last) {
            uint4 nw;
            nw.x = pack2(t0, t1); nw.y = pack2(t2, t3);
            nw.z = pack2(t4, t5); nw.w = pack2(t6, t7);
            *(uint4*)(Nb + base) = nw;
          }
        }
      }
    }
    unsigned short* tmp = Pb; Pb = Cb; Cb = Nb; Nb = tmp;
    if (k < KPOLY) grid.sync();
  }

  // ---- log-softmax from register acc ----
#pragma unroll
  for (int i = 0; i < ROWS_PW; ++i) {
    int row = row0 + i;
    if (row < n && g == (i & 7)) {
      float m = acc[i >> 3][0];
#pragma unroll
      for (int j = 1; j < 8; ++j) m = fmaxf(m, acc[i >> 3][j]);
      m = fmaxf(m, __shfl_xor(m, 1, 64));
      m = fmaxf(m, __shfl_xor(m, 2, 64));
      m = fmaxf(m, __shfl_xor(m, 4, 64));
      float ss = 0.0f;
#pragma unroll
      for (int j = 0; j < 8; ++j) ss += expf(acc[i >> 3][j] - m);
      ss += __shfl_xor(ss, 1, 64);
      ss += __shfl_xor(ss, 2, 64);
      ss += __shfl_xor(ss, 4, 64);
      float lg = m + logf(ss);
      size_t base = (size_t)row * NCLS + (p << 3);
      float4 o0, o1;
      o0.x = acc[i >> 3][0] - lg; o0.y = acc[i >> 3][1] - lg;
      o0.z = acc[i >> 3][2] - lg; o0.w = acc[i >> 3][3] - lg;
      o1.x = acc[i >> 3][4] - lg; o1.y = acc[i >> 3][5] - lg;
      o1.z = acc[i >> 3][6] - lg; o1.w = acc[i >> 3][7] - lg;
      *(float4*)(out + base) = o0;
      *(float4*)(out + base + 4) = o1;
    }
  }
}

// ------------- fallback (non-cooperative) SpMM pass kernels (round-6 proven) -------------
__global__ void spmm_first(const int* __restrict__ rowptr, const int2* __restrict__ ecw,
                           const unsigned short* __restrict__ h, unsigned short* __restrict__ tx1,
                           float* __restrict__ acc, const float* __restrict__ cw, int n) {
  int wid = (blockIdx.x * blockDim.x + threadIdx.x) >> 6;
  int lane = threadIdx.x & 63;
  if (wid >= n) return;
  int p = lane & 7, g = lane >> 3;
  float s[8];
  gather_row8(rowptr, ecw, h, wid, p, s);
  if (g == 0) {
    size_t base = (size_t)wid * NCLS + (p << 3);
    uint4 hv = *(const uint4*)(h + base);
    float c0 = cw[0], c1 = cw[1];
    float4 a0, a1;
    a0.x = c0 * u2f_lo(hv.x) + c1 * s[0]; a0.y = c0 * u2f_hi(hv.x) + c1 * s[1];
    a0.z = c0 * u2f_lo(hv.y) + c1 * s[2]; a0.w = c0 * u2f_hi(hv.y) + c1 * s[3];
    a1.x = c0 * u2f_lo(hv.z) + c1 * s[4]; a1.y = c0 * u2f_hi(hv.z) + c1 * s[5];
    a1.z = c0 * u2f_lo(hv.w) + c1 * s[6]; a1.w = c0 * u2f_hi(hv.w) + c1 * s[7];
    *(float4*)(acc + base) = a0;
    *(float4*)(acc + base + 4) = a1;
    uint4 tw;
    tw.x = pack2(s[0], s[1]); tw.y = pack2(s[2], s[3]);
    tw.z = pack2(s[4], s[5]); tw.w = pack2(s[6], s[7]);
    *(uint4*)(tx1 + base) = tw;
  }
}

__global__ void spmm_step(const int* __restrict__ rowptr, const int2* __restrict__ ecw,
                          const unsigned short* __restrict__ curb,
                          const unsigned short* __restrict__ prevb,
                          unsigned short* __restrict__ nextb, float* __restrict__ acc,
                          const float* __restrict__ cw, int k, int last, int n) {
  int wid = (blockIdx.x * blockDim.x + threadIdx.x) >> 6;
  int lane = threadIdx.x & 63;
  if (wid >= n) return;
  int p = lane & 7, g = lane >> 3;
  float s[8];
  gather_row8(rowptr, ecw, curb, wid, p, s);
  if (g == 0) {
    size_t base = (size_t)wid * NCLS + (p << 3);
    uint4 pv = *(const uint4*)(prevb + base);
    float t[8];
    t[0] = 2.0f * s[0] - u2f_lo(pv.x); t[1] = 2.0f * s[1] - u2f_hi(pv.x);
    t[2] = 2.0f * s[2] - u2f_lo(pv.y); t[3] = 2.0f * s[3] - u2f_hi(pv.y);
    t[4] = 2.0f * s[4] - u2f_lo(pv.z); t[5] = 2.0f * s[5] - u2f_hi(pv.z);
    t[6] = 2.0f * s[6] - u2f_lo(pv.w); t[7] = 2.0f * s[7] - u2f_hi(pv.w);
    float ck = cw[k];
    if (!last) {
      uint4 nw;
      nw.x = pack2(t[0], t[1]); nw.y = pack2(t[2], t[3]);
      nw.z = pack2(t[4], t[5]); nw.w = pack2(t[6], t[7]);
      *(uint4*)(nextb + base) = nw;
      float4 a0 = *(const float4*)(acc + base);
      float4 a1 = *(const float4*)(acc + base + 4);
      a0.x = fmaf(ck, t[0], a0.x); a0.y = fmaf(ck, t[1], a0.y);
      a0.z = fmaf(ck, t[2], a0.z); a0.w = fmaf(ck, t[3], a0.w);
      a1.x = fmaf(ck, t[4], a1.x); a1.y = fmaf(ck, t[5], a1.y);
      a1.z = fmaf(ck, t[6], a1.z); a1.w = fmaf(ck, t[7], a1.w);
      *(float4*)(acc + base) = a0;
      *(float4*)(acc + base + 4) = a1;
    } else {
      float4 a0 = *(const float4*)(acc + base);
      float4 a1 = *(const float4*)(acc + base + 4);
      float v[8];
      v[0] = fmaf(ck, t[0], a0.x); v[1] = fmaf(ck, t[1], a0.y);
      v[2] = fmaf(ck, t[2], a0.z); v[3] = fmaf(ck, t[3], a0.w);
      v[4] = fmaf(ck, t[4], a1.x); v[5] = fmaf(ck, t[5], a1.y);
      v[6] = fmaf(ck, t[6], a1.z); v[7] = fmaf(ck, t[7], a1.w);
      float m = v[0];
#pragma unroll
      for (int i = 1; i < 8; ++i) m = fmaxf(m, v[i]);
      m = fmaxf(m, __shfl_xor(m, 1, 64));
      m = fmaxf(m, __shfl_xor(m, 2, 64));
      m = fmaxf(m, __shfl_xor(m, 4, 64));
      float ss = 0.0f;
#pragma unroll
      for (int i = 0; i < 8; ++i) ss += expf(v[i] - m);
      ss += __shfl_xor(ss, 1, 64);
      ss += __shfl_xor(ss, 2, 64);
      ss += __shfl_xor(ss, 4, 64);
      float lg = m + logf(ss);
      float4 o0, o1;
      o0.x = v[0] - lg; o0.y = v[1] - lg; o0.z = v[2] - lg; o0.w = v[3] - lg;
      o1.x = v[4] - lg; o1.y = v[5] - lg; o1.z = v[6] - lg; o1.w = v[7] - lg;
      *(float4*)(acc + base) = o0;
      *(float4*)(acc + base + 4) = o1;
    }
  }
}

// ------------------------- launch -------------------------
extern "C" void kernel_launch(void* const* d_in, const int* in_sizes, int n_in,
                              void* d_out, int out_size, void* d_ws, size_t ws_size,
                              hipStream_t stream) {
  const float* x  = (const float*)d_in[0];
  const int*   ei = (const int*)d_in[1];
  const float* W1 = (const float*)d_in[2];
  const float* W2 = (const float*)d_in[3];
  const float* cw = (const float*)d_in[4];
  float* out = (float*)d_out;

  const int n = in_sizes[0] / NFEAT;     // 100000
  const int E = in_sizes[1] / 2;         // 1600000

  size_t off = 0;
  auto alloc = [&](size_t bytes) { size_t o = off; off += (bytes + 255) & ~(size_t)255; return o; };
  char* w = (char*)d_ws;
  size_t o_deg   = alloc((size_t)n * 4);
  size_t o_cnt   = alloc((size_t)n * 4);
  size_t o_cur   = alloc((size_t)n * 4);
  size_t o_dinv  = alloc((size_t)n * 4);
  size_t o_rp    = alloc((size_t)(n + 1) * 4);
  size_t o_bs    = alloc(4096 * 4);
  size_t o_w1fh  = alloc((size_t)KPAD * NHID * 2);
  size_t o_w1fl  = alloc((size_t)KPAD * NHID * 2);
  size_t o_w2f   = alloc((size_t)NHID * NCLS * 2);
  size_t o_ecw   = alloc((size_t)E * 8);
  size_t o_bufH  = alloc((size_t)n * NCLS * 2);
  size_t o_bufA  = alloc((size_t)n * NCLS * 2);
  size_t o_bufB  = alloc((size_t)n * NCLS * 2);

  int*   deg    = (int*)(w + o_deg);
  int*   cnt    = (int*)(w + o_cnt);
  int*   curi   = (int*)(w + o_cur);
  float* dinv   = (float*)(w + o_dinv);
  int*   rowptr = (int*)(w + o_rp);
  int*   bsums  = (int*)(w + o_bs);
  unsigned short* W1Fh = (unsigned short*)(w + o_w1fh);
  unsigned short* W1Fl = (unsigned short*)(w + o_w1fl);
  unsigned short* W2F  = (unsigned short*)(w + o_w2f);
  int2*  ecw    = (int2*)(w + o_ecw);
  unsigned short* bufH = (unsigned short*)(w + o_bufH);
  unsigned short* bufA = (unsigned short*)(w + o_bufA);
  unsigned short* bufB = (unsigned short*)(w + o_bufB);

  hipMemsetAsync(w + o_deg, 0, o_dinv - o_deg, stream);

  const int nb = (n + 255) / 256;

  conv_w1f<<<(KPAD * NHID + 255) / 256, 256, 0, stream>>>(W1, W1Fh, W1Fl);
  conv_w2f<<<(NHID * NCLS + 255) / 256, 256, 0, stream>>>(W2, W2F);

  edge_count<<<1024, 256, 0, stream>>>(ei, E, deg, cnt);
  make_dinv<<<nb, 256, 0, stream>>>(deg, dinv, n);
  scan_block<<<nb, 256, 0, stream>>>(cnt, rowptr, bsums, n);
  scan_sums<<<1, 1, 0, stream>>>(bsums, nb, rowptr);
  scan_add<<<nb, 256, 0, stream>>>(rowptr, bsums, n);
  scatter_edges<<<1024, 256, 0, stream>>>(ei, E, dinv, rowptr, curi, ecw);

  mlp_mfma<<<(n + 63) / 64, 256, 0, stream>>>(x, W1Fh, W1Fl, W2F, bufH, n);

  // ---- Chebyshev chain: cooperative if resources allow, else multi-kernel ----
  bool coop_ok = false;
  {
    int maxPerCU = 0;
    hipError_t e1 = hipOccupancyMaxActiveBlocksPerMultiprocessor(
        &maxPerCU, (const void*)spmm_chain, 256, 0);
    if (e1 == hipSuccess && maxPerCU >= 4) {
      const int* rp_ = rowptr;
      const int2* ecw_ = ecw;
      unsigned short* b0_ = bufH;
      unsigned short* b1_ = bufA;
      unsigned short* b2_ = bufB;
      float* out_ = out;
      const float* cw_ = cw;
      int n_ = n;
      void* args[] = {(void*)&rp_, (void*)&ecw_, (void*)&b0_, (void*)&b1_,
                      (void*)&b2_, (void*)&out_, (void*)&cw_, (void*)&n_};
      hipError_t e2 = hipLaunchCooperativeKernel((const void*)spmm_chain, dim3(NBLK),
                                                 dim3(256), args, 0, stream);
      coop_ok = (e2 == hipSuccess);
    }
  }

  if (!coop_ok) {
    const int spmm_blocks = (n + 3) / 4;
    spmm_first<<<spmm_blocks, 256, 0, stream>>>(rowptr, ecw, bufH, bufA, out, cw, n);
    unsigned short* P = bufH;
    unsigned short* C = bufA;
    unsigned short* N = bufB;
    for (int k = 2; k <= KPOLY; ++k) {
      spmm_step<<<spmm_blocks, 256, 0, stream>>>(rowptr, ecw, C, P, N, out, cw, k,
                                                 (k == KPOLY) ? 1 : 0, n);
      unsigned short* t = P; P = C; C = N; N = t;
    }
  }
}